// Round 9
// baseline (152.215 us; speedup 1.0000x reference)
//
#include <hip/hip_runtime.h>
#include <math.h>

// B=2, L=512, C=768, C/3=256, pairDim=128
// mo/mt stored in ws as [B,32,L,64] _Float16 (4 MB each)
// MEASUREMENT ROUND: k2 launched twice (idempotent) to solve for k1/k2 split:
//   k2 = dur(this) - dur(R4);  k1 = dur(R4) - k2.

typedef __attribute__((ext_vector_type(8))) _Float16 half8;
typedef __attribute__((ext_vector_type(4))) _Float16 half4;
typedef __attribute__((ext_vector_type(4))) float f32x4;

#define MFMA_F16(a,b,c) __builtin_amdgcn_mfma_f32_16x16x32_f16((a),(b),(c),0,0,0)

static __device__ inline unsigned pack2f16(float a, float b) {
    _Float16 ha = (_Float16)a, hb = (_Float16)b;
    unsigned short ua = __builtin_bit_cast(unsigned short, ha);
    unsigned short ub = __builtin_bit_cast(unsigned short, hb);
    return (unsigned)ua | ((unsigned)ub << 16);
}

static __device__ inline half8 cvt8(float4 u, float4 v) {
    half8 h;
    h[0] = (_Float16)u.x; h[1] = (_Float16)u.y; h[2] = (_Float16)u.z; h[3] = (_Float16)u.w;
    h[4] = (_Float16)v.x; h[5] = (_Float16)v.y; h[6] = (_Float16)v.z; h[7] = (_Float16)v.w;
    return h;
}

__global__ __launch_bounds__(256) void k1_rowstage(
    const float* __restrict__ x, const float* __restrict__ ln_w, const float* __restrict__ ln_b,
    const float* __restrict__ W1, const float* __restrict__ b1,
    const float* __restrict__ Wa, const float* __restrict__ ba,
    _Float16* __restrict__ mo_g, _Float16* __restrict__ mt_g)
{
    const int bl  = blockIdx.x;          // b*512 + l
    const int tid = threadIdx.x;
    const int b   = bl >> 9;
    const int l   = bl & 511;
    const int w   = tid >> 6;
    const int lane = tid & 63;
    const int lr  = lane & 15;
    const int lk  = lane >> 4;

    __shared__ float hs[768];
    __shared__ float ts[768];
    __shared__ float mos[32 * 68];       // padded stride 68 (2-way max on b128 frag reads)
    __shared__ float ws1[4], ws2[4];

    const float* xrow = x + (size_t)bl * 768;
    float v0 = xrow[tid], v1 = xrow[tid + 256], v2 = xrow[tid + 512];

    // Wa fragments for GEMM2 (A-operand: row d = w*16+lr, k-slice e = ks*32+lk*8)
    half8 waf[2];
    #pragma unroll
    for (int ks = 0; ks < 2; ++ks) {
        const float* wp = Wa + (size_t)(w * 16 + lr) * 64 + ks * 32 + lk * 8;
        waf[ks] = cvt8(*(const float4*)wp, *(const float4*)(wp + 4));
    }
    const float4 baq = *(const float4*)(ba + w * 16 + lk * 4);

    // LayerNorm stats
    float s1 = v0 + v1 + v2;
    float s2 = v0 * v0 + v1 * v1 + v2 * v2;
    #pragma unroll
    for (int off = 32; off > 0; off >>= 1) {
        s1 += __shfl_down(s1, off);
        s2 += __shfl_down(s2, off);
    }
    if ((tid & 63) == 0) { ws1[tid >> 6] = s1; ws2[tid >> 6] = s2; }
    __syncthreads();
    float tot1 = ws1[0] + ws1[1] + ws1[2] + ws1[3];
    float tot2 = ws2[0] + ws2[1] + ws2[2] + ws2[3];
    float mu   = tot1 * (1.0f / 768.0f);
    float var  = tot2 * (1.0f / 768.0f) - mu * mu;
    float rstd = rsqrtf(var + 1e-6f);

    hs[tid]       = (v0 - mu) * rstd * ln_w[tid]       + ln_b[tid];
    hs[tid + 256] = (v1 - mu) * rstd * ln_w[tid + 256] + ln_b[tid + 256];
    hs[tid + 512] = (v2 - mu) * rstd * ln_w[tid + 512] + ln_b[tid + 512];
    __syncthreads();

    // GEMM1 (f32 VALU): t[k][j] = h[k] . W1[j,:] + b1[j]
    {
        float a0 = 0.f, a1 = 0.f, a2 = 0.f;
        const float4* wrow = (const float4*)(W1 + (size_t)tid * 256);
        const float4* h0 = (const float4*)(hs);
        const float4* h1 = (const float4*)(hs + 256);
        const float4* h2 = (const float4*)(hs + 512);
        #pragma unroll 8
        for (int i4 = 0; i4 < 64; i4++) {
            float4 wv = wrow[i4];
            float4 x0 = h0[i4], x1 = h1[i4], x2 = h2[i4];
            a0 += x0.x * wv.x + x0.y * wv.y + x0.z * wv.z + x0.w * wv.w;
            a1 += x1.x * wv.x + x1.y * wv.y + x1.z * wv.z + x1.w * wv.w;
            a2 += x2.x * wv.x + x2.y * wv.y + x2.z * wv.z + x2.w * wv.w;
        }
        float bb = b1[tid];
        ts[tid]       = a0 + bb;
        ts[tid + 256] = a1 + bb;
        ts[tid + 512] = a2 + bb;
    }
    __syncthreads();

    // outer product -> mos (LDS, padded) + mo_g (f16)
    {
        const int c = tid >> 3, i = tid & 7;
        float ti0 = ts[c * 8 + i], ti1 = ts[256 + c * 8 + i], ti2 = ts[512 + c * 8 + i];
        half8 h8;
        #pragma unroll
        for (int j = 0; j < 8; j++) {
            float m = (ti0 * ts[c * 8 + j] + ti1 * ts[256 + c * 8 + j] + ti2 * ts[512 + c * 8 + j]) * (1.0f / 3.0f);
            mos[c * 68 + i * 8 + j] = m;
            h8[j] = (_Float16)m;
        }
        size_t mobase = ((size_t)(b * 32 + c) * 512 + l) * 64 + i * 8;
        *(half8*)(mo_g + mobase) = h8;
    }
    __syncthreads();

    // GEMM2 (MFMA): mt[d][c] = gelu( sum_e Wa[d][e]*mo[c][e] + ba[d] )
    #pragma unroll
    for (int nt = 0; nt < 2; ++nt) {
        f32x4 acc = { baq.x, baq.y, baq.z, baq.w };
        #pragma unroll
        for (int ks = 0; ks < 2; ++ks) {
            const float* mp = &mos[(nt * 16 + lr) * 68 + ks * 32 + lk * 8];
            half8 mof = cvt8(*(const float4*)mp, *(const float4*)(mp + 4));
            acc = MFMA_F16(waf[ks], mof, acc);
        }
        half4 o;
        #pragma unroll
        for (int j = 0; j < 4; ++j) {
            float g = 0.5f * acc[j] * (1.0f + erff(acc[j] * 0.70710678118654752f));
            o[j] = (_Float16)g;
        }
        *(half4*)(mt_g + ((size_t)(b * 32 + nt * 16 + lr) * 512 + l) * 64 + w * 16 + lk * 4) = o;
    }
}

// k2 (R4 verbatim): per (32 l x 16 m) tile:
//   phase A (MFMA): raw[pair][c] = MO[c,l,:].MT[c,m,:] -> f16 in LDS (pad 40, XOR-swizzled)
//   phase B (MFMA): D[p][pair] = W2 . raw; per-wave LDS transpose ->
//                   8 x 1KB-contiguous nontemporal f32x4 stores per l-row
__global__ __launch_bounds__(256, 2) void k2_mfma(
    const _Float16* __restrict__ mo, const _Float16* __restrict__ mt,
    const float* __restrict__ W2, const float* __restrict__ b2,
    float* __restrict__ out)
{
    __shared__ _Float16 raw16[512 * 40];   // [pair][c], 80B rows, 40 KB
    __shared__ float sc[4][2048];          // per-wave 8KB transpose scratch, 32 KB

    const int tid  = threadIdx.x;
    const int w    = tid >> 6;
    const int lane = tid & 63;
    const int lr   = lane & 15;
    const int lk   = lane >> 4;

    // bijective XCD swizzle (nwg=1024, 1024%8==0)
    const int flat = blockIdx.x;
    const int nf   = (flat & 7) * 128 + (flat >> 3);
    const int m0   = (nf & 31) << 4;        // 32 m-tiles of 16
    const int l0   = ((nf >> 5) & 15) << 5; // 16 l-tiles of 32
    const int b    = nf >> 9;

    // ---- phase A: wave w computes c in [8w, 8w+8), all 512 pairs ----
    #pragma unroll
    for (int cp = 0; cp < 4; ++cp) {
        const int c0 = w * 8 + cp * 2;
        f32x4 acc[2][2] = {};   // [ci][rh]
        #pragma unroll
        for (int ci = 0; ci < 2; ++ci) {
            const int c = c0 + ci;
            const _Float16* mo_c = mo + (((size_t)(b * 32 + c) * 512) + l0) * 64;
            const _Float16* mt_c = mt + (((size_t)(b * 32 + c) * 512) + m0) * 64;
            #pragma unroll
            for (int ks = 0; ks < 2; ++ks) {
                half8 bfrag = *(const half8*)(mt_c + (size_t)lr * 64 + ks * 32 + lk * 8);
                #pragma unroll
                for (int rh = 0; rh < 2; ++rh) {
                    half8 afrag = *(const half8*)(mo_c + (size_t)(rh * 16 + lr) * 64 + ks * 32 + lk * 8);
                    acc[ci][rh] = MFMA_F16(afrag, bfrag, acc[ci][rh]);
                }
            }
        }
        // park raw tile: pair = l_local*16 + m_local; D: row(l)=lk*4+j, col(m)=lr
        #pragma unroll
        for (int rh = 0; rh < 2; ++rh) {
            #pragma unroll
            for (int j = 0; j < 4; ++j) {
                int pair = (rh * 16 + lk * 4 + j) * 16 + lr;
                int sw   = (((pair >> 3) & 1) << 3) | (((pair >> 6) & 1) << 4);
                *(unsigned*)&raw16[pair * 40 + (c0 ^ sw)] = pack2f16(acc[0][rh][j], acc[1][rh][j]);
            }
        }
    }

    // W2 fragments (A-operand: row p = c8*16+lr, k-slice c = lk*8) + bias quads
    half8 wfrag[8]; float4 b2q[8];
    #pragma unroll
    for (int c8 = 0; c8 < 8; ++c8) {
        const float* wp = W2 + (size_t)(c8 * 16 + lr) * 32 + lk * 8;
        wfrag[c8] = cvt8(*(const float4*)wp, *(const float4*)(wp + 4));
        b2q[c8]   = *(const float4*)(b2 + c8 * 16 + lk * 4);
    }
    __syncthreads();

    // ---- phase B: wave w handles l-rows r in [8w, 8w+8) ----
    for (int i = 0; i < 8; ++i) {
        const int r  = w * 8 + i;
        const int pr = r * 16 + lr;
        const int swr = (((pr >> 3) & 1) << 3) | (((pr >> 6) & 1) << 4);
        half8 a = *(const half8*)&raw16[pr * 40 + ((lk * 8) ^ swr)];   // B-frag: col=pair(m), k=c

        // compute D[p][m] for 16 m, 128 p; park in per-wave swizzled scratch
        #pragma unroll
        for (int c8 = 0; c8 < 8; ++c8) {
            f32x4 d = { b2q[c8].x, b2q[c8].y, b2q[c8].z, b2q[c8].w };
            d = MFMA_F16(wfrag[c8], a, d);
            // lane (lr,lk) holds p = c8*16+lk*4+j for m = lr
            int chunk = (c8 * 4 + lk) ^ lr;        // 16B-chunk swizzle by m-row
            *(f32x4*)&sc[w][lr * 128 + chunk * 4] = d;
        }
        // read back in store order: 8 x 1KB contiguous (full 8KB region for this l-row)
        float* ob = out + (((size_t)(b * 512 + l0 + r)) * 512 + m0) * 128;
        #pragma unroll
        for (int s = 0; s < 8; ++s) {
            int mm = s * 2 + (lane >> 5);
            int cp = (lane & 31) ^ mm;
            f32x4 v = *(const f32x4*)&sc[w][mm * 128 + cp * 4];
            __builtin_nontemporal_store(v, (f32x4*)(ob + s * 256 + lane * 4));
        }
    }
}

extern "C" void kernel_launch(void* const* d_in, const int* in_sizes, int n_in,
                              void* d_out, int out_size, void* d_ws, size_t ws_size,
                              hipStream_t stream) {
    const float* x    = (const float*)d_in[0];
    const float* ln_w = (const float*)d_in[1];
    const float* ln_b = (const float*)d_in[2];
    const float* W1   = (const float*)d_in[3];
    const float* b1   = (const float*)d_in[4];
    const float* Wa   = (const float*)d_in[5];
    const float* ba   = (const float*)d_in[6];
    const float* W2   = (const float*)d_in[7];
    const float* b2   = (const float*)d_in[8];
    float* out = (float*)d_out;

    _Float16* mo = (_Float16*)d_ws;                     // [2,32,512,64] f16 = 4 MB
    _Float16* mt = mo + (size_t)2 * 32 * 512 * 64;      // [2,32,512,64] f16 = 4 MB

    k1_rowstage<<<1024, 256, 0, stream>>>(x, ln_w, ln_b, W1, b1, Wa, ba, mo, mt);
    // k2 launched TWICE (idempotent): dur delta vs R4 gives k2's standalone time.
    k2_mfma<<<1024, 256, 0, stream>>>(mo, mt, W2, b2, out);
    k2_mfma<<<1024, 256, 0, stream>>>(mo, mt, W2, b2, out);
}

// Round 10
// 85.063 us; speedup vs baseline: 1.7894x; 1.7894x over previous
//
#include <hip/hip_runtime.h>
#include <math.h>

// B=2, L=512, C=768, C/3=256, pairDim=128
// ws layout: mo [2,32,512,64] f16 (4 MB) | mt same (4 MB) | W1P f32 256 KB
// W1P = W1 packed to fragment order: panel p=j>>6, chunk i4, lane j&63, 4 f32
//   -> GEMM1 wave loads are 1KB-contiguous (1 txn/instr) instead of 64-way split.

typedef __attribute__((ext_vector_type(8))) _Float16 half8;
typedef __attribute__((ext_vector_type(4))) _Float16 half4;
typedef __attribute__((ext_vector_type(4))) float f32x4;

#define MFMA_F16(a,b,c) __builtin_amdgcn_mfma_f32_16x16x32_f16((a),(b),(c),0,0,0)

static __device__ inline unsigned pack2f16(float a, float b) {
    _Float16 ha = (_Float16)a, hb = (_Float16)b;
    unsigned short ua = __builtin_bit_cast(unsigned short, ha);
    unsigned short ub = __builtin_bit_cast(unsigned short, hb);
    return (unsigned)ua | ((unsigned)ub << 16);
}

static __device__ inline half8 cvt8(float4 u, float4 v) {
    half8 h;
    h[0] = (_Float16)u.x; h[1] = (_Float16)u.y; h[2] = (_Float16)u.z; h[3] = (_Float16)u.w;
    h[4] = (_Float16)v.x; h[5] = (_Float16)v.y; h[6] = (_Float16)v.z; h[7] = (_Float16)v.w;
    return h;
}

// k0: pack W1 [256][256] f32 -> W1P [4][64][64][4] f32 (fragment order)
__global__ __launch_bounds__(256) void k0_pack(const float* __restrict__ W1, float* __restrict__ W1P)
{
    int flat4 = blockIdx.x * 256 + threadIdx.x;   // 0..16383 float4s
    int j = flat4 >> 6, i4 = flat4 & 63;
    float4 v = ((const float4*)W1)[flat4];
    ((float4*)W1P)[(j >> 6) * 4096 + i4 * 64 + (j & 63)] = v;
}

__global__ __launch_bounds__(256) void k1_rowstage(
    const float* __restrict__ x, const float* __restrict__ ln_w, const float* __restrict__ ln_b,
    const float* __restrict__ W1P, const float* __restrict__ b1,
    const float* __restrict__ Wa, const float* __restrict__ ba,
    _Float16* __restrict__ mo_g, _Float16* __restrict__ mt_g)
{
    const int bl  = blockIdx.x;          // b*512 + l
    const int tid = threadIdx.x;
    const int b   = bl >> 9;
    const int l   = bl & 511;
    const int w   = tid >> 6;
    const int lane = tid & 63;
    const int lr  = lane & 15;
    const int lk  = lane >> 4;

    __shared__ float hs[768];
    __shared__ float ts[768];
    __shared__ float mos[32 * 68];       // padded stride 68 (2-way max on b128 frag reads)
    __shared__ float ws1[4], ws2[4];

    const float* xrow = x + (size_t)bl * 768;
    float v0 = xrow[tid], v1 = xrow[tid + 256], v2 = xrow[tid + 512];

    // Wa fragments for GEMM2 (A-operand: row d = w*16+lr, k-slice e = ks*32+lk*8)
    half8 waf[2];
    #pragma unroll
    for (int ks = 0; ks < 2; ++ks) {
        const float* wp = Wa + (size_t)(w * 16 + lr) * 64 + ks * 32 + lk * 8;
        waf[ks] = cvt8(*(const float4*)wp, *(const float4*)(wp + 4));
    }
    const float4 baq = *(const float4*)(ba + w * 16 + lk * 4);

    // LayerNorm stats
    float s1 = v0 + v1 + v2;
    float s2 = v0 * v0 + v1 * v1 + v2 * v2;
    #pragma unroll
    for (int off = 32; off > 0; off >>= 1) {
        s1 += __shfl_down(s1, off);
        s2 += __shfl_down(s2, off);
    }
    if ((tid & 63) == 0) { ws1[tid >> 6] = s1; ws2[tid >> 6] = s2; }
    __syncthreads();
    float tot1 = ws1[0] + ws1[1] + ws1[2] + ws1[3];
    float tot2 = ws2[0] + ws2[1] + ws2[2] + ws2[3];
    float mu   = tot1 * (1.0f / 768.0f);
    float var  = tot2 * (1.0f / 768.0f) - mu * mu;
    float rstd = rsqrtf(var + 1e-6f);

    hs[tid]       = (v0 - mu) * rstd * ln_w[tid]       + ln_b[tid];
    hs[tid + 256] = (v1 - mu) * rstd * ln_w[tid + 256] + ln_b[tid + 256];
    hs[tid + 512] = (v2 - mu) * rstd * ln_w[tid + 512] + ln_b[tid + 512];
    __syncthreads();

    // GEMM1 (f32 VALU): t[k][j] = h[k] . W1[j,:] + b1[j]
    // W1 row j read from W1P fragment order: 1KB-contiguous per wave-load.
    {
        float a0 = 0.f, a1 = 0.f, a2 = 0.f;
        const float4* wrow = (const float4*)(W1P + ((size_t)(tid >> 6) << 14) + ((tid & 63) << 2));
        const float4* h0 = (const float4*)(hs);
        const float4* h1 = (const float4*)(hs + 256);
        const float4* h2 = (const float4*)(hs + 512);
        #pragma unroll 8
        for (int i4 = 0; i4 < 64; i4++) {
            float4 wv = wrow[i4 * 64];
            float4 x0 = h0[i4], x1 = h1[i4], x2 = h2[i4];
            a0 += x0.x * wv.x + x0.y * wv.y + x0.z * wv.z + x0.w * wv.w;
            a1 += x1.x * wv.x + x1.y * wv.y + x1.z * wv.z + x1.w * wv.w;
            a2 += x2.x * wv.x + x2.y * wv.y + x2.z * wv.z + x2.w * wv.w;
        }
        float bb = b1[tid];
        ts[tid]       = a0 + bb;
        ts[tid + 256] = a1 + bb;
        ts[tid + 512] = a2 + bb;
    }
    __syncthreads();

    // outer product -> mos (LDS, padded) + mo_g (f16)
    {
        const int c = tid >> 3, i = tid & 7;
        float ti0 = ts[c * 8 + i], ti1 = ts[256 + c * 8 + i], ti2 = ts[512 + c * 8 + i];
        half8 h8;
        #pragma unroll
        for (int j = 0; j < 8; j++) {
            float m = (ti0 * ts[c * 8 + j] + ti1 * ts[256 + c * 8 + j] + ti2 * ts[512 + c * 8 + j]) * (1.0f / 3.0f);
            mos[c * 68 + i * 8 + j] = m;
            h8[j] = (_Float16)m;
        }
        size_t mobase = ((size_t)(b * 32 + c) * 512 + l) * 64 + i * 8;
        *(half8*)(mo_g + mobase) = h8;
    }
    __syncthreads();

    // GEMM2 (MFMA): mt[d][c] = gelu( sum_e Wa[d][e]*mo[c][e] + ba[d] )
    #pragma unroll
    for (int nt = 0; nt < 2; ++nt) {
        f32x4 acc = { baq.x, baq.y, baq.z, baq.w };
        #pragma unroll
        for (int ks = 0; ks < 2; ++ks) {
            const float* mp = &mos[(nt * 16 + lr) * 68 + ks * 32 + lk * 8];
            half8 mof = cvt8(*(const float4*)mp, *(const float4*)(mp + 4));
            acc = MFMA_F16(waf[ks], mof, acc);
        }
        half4 o;
        #pragma unroll
        for (int j = 0; j < 4; ++j) {
            float g = 0.5f * acc[j] * (1.0f + erff(acc[j] * 0.70710678118654752f));
            o[j] = (_Float16)g;
        }
        *(half4*)(mt_g + ((size_t)(b * 32 + nt * 16 + lr) * 512 + l) * 64 + w * 16 + lk * 4) = o;
    }
}

// k2 (R4 verbatim): per (32 l x 16 m) tile:
//   phase A (MFMA): raw[pair][c] = MO[c,l,:].MT[c,m,:] -> f16 in LDS (pad 40, XOR-swizzled)
//   phase B (MFMA): D[p][pair] = W2 . raw; per-wave LDS transpose ->
//                   8 x 1KB-contiguous nontemporal f32x4 stores per l-row
__global__ __launch_bounds__(256, 2) void k2_mfma(
    const _Float16* __restrict__ mo, const _Float16* __restrict__ mt,
    const float* __restrict__ W2, const float* __restrict__ b2,
    float* __restrict__ out)
{
    __shared__ _Float16 raw16[512 * 40];   // [pair][c], 80B rows, 40 KB
    __shared__ float sc[4][2048];          // per-wave 8KB transpose scratch, 32 KB

    const int tid  = threadIdx.x;
    const int w    = tid >> 6;
    const int lane = tid & 63;
    const int lr   = lane & 15;
    const int lk   = lane >> 4;

    // bijective XCD swizzle (nwg=1024, 1024%8==0)
    const int flat = blockIdx.x;
    const int nf   = (flat & 7) * 128 + (flat >> 3);
    const int m0   = (nf & 31) << 4;        // 32 m-tiles of 16
    const int l0   = ((nf >> 5) & 15) << 5; // 16 l-tiles of 32
    const int b    = nf >> 9;

    // ---- phase A: wave w computes c in [8w, 8w+8), all 512 pairs ----
    #pragma unroll
    for (int cp = 0; cp < 4; ++cp) {
        const int c0 = w * 8 + cp * 2;
        f32x4 acc[2][2] = {};   // [ci][rh]
        #pragma unroll
        for (int ci = 0; ci < 2; ++ci) {
            const int c = c0 + ci;
            const _Float16* mo_c = mo + (((size_t)(b * 32 + c) * 512) + l0) * 64;
            const _Float16* mt_c = mt + (((size_t)(b * 32 + c) * 512) + m0) * 64;
            #pragma unroll
            for (int ks = 0; ks < 2; ++ks) {
                half8 bfrag = *(const half8*)(mt_c + (size_t)lr * 64 + ks * 32 + lk * 8);
                #pragma unroll
                for (int rh = 0; rh < 2; ++rh) {
                    half8 afrag = *(const half8*)(mo_c + (size_t)(rh * 16 + lr) * 64 + ks * 32 + lk * 8);
                    acc[ci][rh] = MFMA_F16(afrag, bfrag, acc[ci][rh]);
                }
            }
        }
        // park raw tile: pair = l_local*16 + m_local; D: row(l)=lk*4+j, col(m)=lr
        #pragma unroll
        for (int rh = 0; rh < 2; ++rh) {
            #pragma unroll
            for (int j = 0; j < 4; ++j) {
                int pair = (rh * 16 + lk * 4 + j) * 16 + lr;
                int sw   = (((pair >> 3) & 1) << 3) | (((pair >> 6) & 1) << 4);
                *(unsigned*)&raw16[pair * 40 + (c0 ^ sw)] = pack2f16(acc[0][rh][j], acc[1][rh][j]);
            }
        }
    }

    // W2 fragments (A-operand: row p = c8*16+lr, k-slice c = lk*8) + bias quads
    half8 wfrag[8]; float4 b2q[8];
    #pragma unroll
    for (int c8 = 0; c8 < 8; ++c8) {
        const float* wp = W2 + (size_t)(c8 * 16 + lr) * 32 + lk * 8;
        wfrag[c8] = cvt8(*(const float4*)wp, *(const float4*)(wp + 4));
        b2q[c8]   = *(const float4*)(b2 + c8 * 16 + lk * 4);
    }
    __syncthreads();

    // ---- phase B: wave w handles l-rows r in [8w, 8w+8) ----
    for (int i = 0; i < 8; ++i) {
        const int r  = w * 8 + i;
        const int pr = r * 16 + lr;
        const int swr = (((pr >> 3) & 1) << 3) | (((pr >> 6) & 1) << 4);
        half8 a = *(const half8*)&raw16[pr * 40 + ((lk * 8) ^ swr)];   // B-frag: col=pair(m), k=c

        // compute D[p][m] for 16 m, 128 p; park in per-wave swizzled scratch
        #pragma unroll
        for (int c8 = 0; c8 < 8; ++c8) {
            f32x4 d = { b2q[c8].x, b2q[c8].y, b2q[c8].z, b2q[c8].w };
            d = MFMA_F16(wfrag[c8], a, d);
            // lane (lr,lk) holds p = c8*16+lk*4+j for m = lr
            int chunk = (c8 * 4 + lk) ^ lr;        // 16B-chunk swizzle by m-row
            *(f32x4*)&sc[w][lr * 128 + chunk * 4] = d;
        }
        // read back in store order: 8 x 1KB contiguous (full 8KB region for this l-row)
        float* ob = out + (((size_t)(b * 512 + l0 + r)) * 512 + m0) * 128;
        #pragma unroll
        for (int s = 0; s < 8; ++s) {
            int mm = s * 2 + (lane >> 5);
            int cp = (lane & 31) ^ mm;
            f32x4 v = *(const f32x4*)&sc[w][mm * 128 + cp * 4];
            __builtin_nontemporal_store(v, (f32x4*)(ob + s * 256 + lane * 4));
        }
    }
}

extern "C" void kernel_launch(void* const* d_in, const int* in_sizes, int n_in,
                              void* d_out, int out_size, void* d_ws, size_t ws_size,
                              hipStream_t stream) {
    const float* x    = (const float*)d_in[0];
    const float* ln_w = (const float*)d_in[1];
    const float* ln_b = (const float*)d_in[2];
    const float* W1   = (const float*)d_in[3];
    const float* b1   = (const float*)d_in[4];
    const float* Wa   = (const float*)d_in[5];
    const float* ba   = (const float*)d_in[6];
    const float* W2   = (const float*)d_in[7];
    const float* b2   = (const float*)d_in[8];
    float* out = (float*)d_out;

    _Float16* mo = (_Float16*)d_ws;                     // [2,32,512,64] f16 = 4 MB
    _Float16* mt = mo + (size_t)2 * 32 * 512 * 64;      // [2,32,512,64] f16 = 4 MB
    float* W1P   = (float*)(mt + (size_t)2 * 32 * 512 * 64);  // 256 KB packed W1

    k0_pack<<<64, 256, 0, stream>>>(W1, W1P);
    k1_rowstage<<<1024, 256, 0, stream>>>(x, ln_w, ln_b, W1P, b1, Wa, ba, mo, mt);
    k2_mfma<<<1024, 256, 0, stream>>>(mo, mt, W2, b2, out);
}

// Round 11
// 78.221 us; speedup vs baseline: 1.9460x; 1.0875x over previous
//
#include <hip/hip_runtime.h>
#include <math.h>

// B=2, L=512, C=768, C/3=256, pairDim=128
// ws layout: mo [2,32,512,64] f16 (4 MB) | mt same (4 MB) | W1H f16 frag-packed 128 KB
// W1H = W1 as f16 in MFMA B-fragment order [nt(16)][ks(8)][lane(64)][8]
//   -> GEMM1 runs on MFMA: 8 ds_read + 32 L2 loads + 32 MFMA per wave
//      (replaces ~192 LDS-broadcast reads + 768 f32 FMA per thread).

typedef __attribute__((ext_vector_type(8))) _Float16 half8;
typedef __attribute__((ext_vector_type(4))) _Float16 half4;
typedef __attribute__((ext_vector_type(4))) float f32x4;

#define MFMA_F16(a,b,c) __builtin_amdgcn_mfma_f32_16x16x32_f16((a),(b),(c),0,0,0)

static __device__ inline unsigned pack2f16(float a, float b) {
    _Float16 ha = (_Float16)a, hb = (_Float16)b;
    unsigned short ua = __builtin_bit_cast(unsigned short, ha);
    unsigned short ub = __builtin_bit_cast(unsigned short, hb);
    return (unsigned)ua | ((unsigned)ub << 16);
}

static __device__ inline half8 cvt8(float4 u, float4 v) {
    half8 h;
    h[0] = (_Float16)u.x; h[1] = (_Float16)u.y; h[2] = (_Float16)u.z; h[3] = (_Float16)u.w;
    h[4] = (_Float16)v.x; h[5] = (_Float16)v.y; h[6] = (_Float16)v.z; h[7] = (_Float16)v.w;
    return h;
}

// k0: W1 [256 j][256 i] f32 -> W1H f16 B-frag order [nt][ks][lane][8]
__global__ __launch_bounds__(256) void k0_pack(const float* __restrict__ W1, _Float16* __restrict__ W1H)
{
    int flat8 = blockIdx.x * 256 + threadIdx.x;   // 0..8191 (8-elem chunks)
    int j  = flat8 >> 5, i8 = flat8 & 31;
    int nt = j >> 4, lr = j & 15, ks = i8 >> 2, lk = i8 & 3;
    const float4* src = (const float4*)(W1 + (size_t)j * 256 + (size_t)i8 * 8);
    half8 h = cvt8(src[0], src[1]);
    *(half8*)(W1H + (((size_t)(nt * 8 + ks) * 64) + lk * 16 + lr) * 8) = h;
}

__global__ __launch_bounds__(256) void k1_rowstage(
    const float* __restrict__ x, const float* __restrict__ ln_w, const float* __restrict__ ln_b,
    const _Float16* __restrict__ W1H, const float* __restrict__ b1,
    const float* __restrict__ Wa, const float* __restrict__ ba,
    _Float16* __restrict__ mo_g, _Float16* __restrict__ mt_g)
{
    const int bl  = blockIdx.x;          // b*512 + l
    const int tid = threadIdx.x;
    const int b   = bl >> 9;
    const int l   = bl & 511;
    const int w   = tid >> 6;
    const int lane = tid & 63;
    const int lr  = lane & 15;
    const int lk  = lane >> 4;

    __shared__ _Float16 hs16[4 * 272];   // h as f16, A-frag layout; stride 272 (2-way max)
    __shared__ float ts[768];
    __shared__ float mos[32 * 68];       // padded stride 68 (2-way max on b128 frag reads)
    __shared__ float ws1[4], ws2[4];

    const float* xrow = x + (size_t)bl * 768;
    float v0 = xrow[tid], v1 = xrow[tid + 256], v2 = xrow[tid + 512];

    // Wa fragments for GEMM2 (A-operand: row d = w*16+lr, k-slice e = ks*32+lk*8)
    half8 waf[2];
    #pragma unroll
    for (int ks = 0; ks < 2; ++ks) {
        const float* wp = Wa + (size_t)(w * 16 + lr) * 64 + ks * 32 + lk * 8;
        waf[ks] = cvt8(*(const float4*)wp, *(const float4*)(wp + 4));
    }
    const float4 baq = *(const float4*)(ba + w * 16 + lk * 4);

    // LayerNorm stats
    float s1 = v0 + v1 + v2;
    float s2 = v0 * v0 + v1 * v1 + v2 * v2;
    #pragma unroll
    for (int off = 32; off > 0; off >>= 1) {
        s1 += __shfl_down(s1, off);
        s2 += __shfl_down(s2, off);
    }
    if ((tid & 63) == 0) { ws1[tid >> 6] = s1; ws2[tid >> 6] = s2; }
    __syncthreads();
    float tot1 = ws1[0] + ws1[1] + ws1[2] + ws1[3];
    float tot2 = ws2[0] + ws2[1] + ws2[2] + ws2[3];
    float mu   = tot1 * (1.0f / 768.0f);
    float var  = tot2 * (1.0f / 768.0f) - mu * mu;
    float rstd = rsqrtf(var + 1e-6f);

    hs16[tid]            = (_Float16)((v0 - mu) * rstd * ln_w[tid]       + ln_b[tid]);
    hs16[272 + tid]      = (_Float16)((v1 - mu) * rstd * ln_w[tid + 256] + ln_b[tid + 256]);
    hs16[544 + tid]      = (_Float16)((v2 - mu) * rstd * ln_w[tid + 512] + ln_b[tid + 512]);
    hs16[816 + tid]      = (_Float16)0.0f;   // zero pad-row 3 (A rows 3..15 unused)
    __syncthreads();

    // GEMM1 (MFMA): t[k][j] = h[k] . W1[j,:] + b1[j]
    // A rows = k-chunk (3 of 16 used), B cols = j; wave w owns N-tiles 4w..4w+3
    {
        f32x4 acc[4] = {};
        #pragma unroll
        for (int ks = 0; ks < 8; ++ks) {
            half8 af = *(const half8*)&hs16[(lr & 3) * 272 + ks * 32 + lk * 8];
            #pragma unroll
            for (int n = 0; n < 4; ++n) {
                half8 bf = *(const half8*)(W1H + (((size_t)((w * 4 + n) * 8 + ks) * 64) + lane) * 8);
                acc[n] = MFMA_F16(af, bf, acc[n]);
            }
        }
        if (lk == 0) {
            #pragma unroll
            for (int n = 0; n < 4; ++n) {
                int j = (w * 4 + n) * 16 + lr;
                float bb = b1[j];
                ts[j]       = acc[n][0] + bb;
                ts[256 + j] = acc[n][1] + bb;
                ts[512 + j] = acc[n][2] + bb;
            }
        }
    }
    __syncthreads();

    // outer product -> mos (LDS, padded) + mo_g (f16)
    {
        const int c = tid >> 3, i = tid & 7;
        float ti0 = ts[c * 8 + i], ti1 = ts[256 + c * 8 + i], ti2 = ts[512 + c * 8 + i];
        half8 h8;
        #pragma unroll
        for (int j = 0; j < 8; j++) {
            float m = (ti0 * ts[c * 8 + j] + ti1 * ts[256 + c * 8 + j] + ti2 * ts[512 + c * 8 + j]) * (1.0f / 3.0f);
            mos[c * 68 + i * 8 + j] = m;
            h8[j] = (_Float16)m;
        }
        size_t mobase = ((size_t)(b * 32 + c) * 512 + l) * 64 + i * 8;
        *(half8*)(mo_g + mobase) = h8;
    }
    __syncthreads();

    // GEMM2 (MFMA): mt[d][c] = gelu( sum_e Wa[d][e]*mo[c][e] + ba[d] )
    #pragma unroll
    for (int nt = 0; nt < 2; ++nt) {
        f32x4 acc = { baq.x, baq.y, baq.z, baq.w };
        #pragma unroll
        for (int ks = 0; ks < 2; ++ks) {
            const float* mp = &mos[(nt * 16 + lr) * 68 + ks * 32 + lk * 8];
            half8 mof = cvt8(*(const float4*)mp, *(const float4*)(mp + 4));
            acc = MFMA_F16(waf[ks], mof, acc);
        }
        half4 o;
        #pragma unroll
        for (int j = 0; j < 4; ++j) {
            float g = 0.5f * acc[j] * (1.0f + erff(acc[j] * 0.70710678118654752f));
            o[j] = (_Float16)g;
        }
        *(half4*)(mt_g + ((size_t)(b * 32 + nt * 16 + lr) * 512 + l) * 64 + w * 16 + lk * 4) = o;
    }
}

// k2 (R4 verbatim): per (32 l x 16 m) tile:
//   phase A (MFMA): raw[pair][c] = MO[c,l,:].MT[c,m,:] -> f16 in LDS (pad 40, XOR-swizzled)
//   phase B (MFMA): D[p][pair] = W2 . raw; per-wave LDS transpose ->
//                   8 x 1KB-contiguous nontemporal f32x4 stores per l-row
__global__ __launch_bounds__(256, 2) void k2_mfma(
    const _Float16* __restrict__ mo, const _Float16* __restrict__ mt,
    const float* __restrict__ W2, const float* __restrict__ b2,
    float* __restrict__ out)
{
    __shared__ _Float16 raw16[512 * 40];   // [pair][c], 80B rows, 40 KB
    __shared__ float sc[4][2048];          // per-wave 8KB transpose scratch, 32 KB

    const int tid  = threadIdx.x;
    const int w    = tid >> 6;
    const int lane = tid & 63;
    const int lr   = lane & 15;
    const int lk   = lane >> 4;

    // bijective XCD swizzle (nwg=1024, 1024%8==0)
    const int flat = blockIdx.x;
    const int nf   = (flat & 7) * 128 + (flat >> 3);
    const int m0   = (nf & 31) << 4;        // 32 m-tiles of 16
    const int l0   = ((nf >> 5) & 15) << 5; // 16 l-tiles of 32
    const int b    = nf >> 9;

    // ---- phase A: wave w computes c in [8w, 8w+8), all 512 pairs ----
    #pragma unroll
    for (int cp = 0; cp < 4; ++cp) {
        const int c0 = w * 8 + cp * 2;
        f32x4 acc[2][2] = {};   // [ci][rh]
        #pragma unroll
        for (int ci = 0; ci < 2; ++ci) {
            const int c = c0 + ci;
            const _Float16* mo_c = mo + (((size_t)(b * 32 + c) * 512) + l0) * 64;
            const _Float16* mt_c = mt + (((size_t)(b * 32 + c) * 512) + m0) * 64;
            #pragma unroll
            for (int ks = 0; ks < 2; ++ks) {
                half8 bfrag = *(const half8*)(mt_c + (size_t)lr * 64 + ks * 32 + lk * 8);
                #pragma unroll
                for (int rh = 0; rh < 2; ++rh) {
                    half8 afrag = *(const half8*)(mo_c + (size_t)(rh * 16 + lr) * 64 + ks * 32 + lk * 8);
                    acc[ci][rh] = MFMA_F16(afrag, bfrag, acc[ci][rh]);
                }
            }
        }
        // park raw tile: pair = l_local*16 + m_local; D: row(l)=lk*4+j, col(m)=lr
        #pragma unroll
        for (int rh = 0; rh < 2; ++rh) {
            #pragma unroll
            for (int j = 0; j < 4; ++j) {
                int pair = (rh * 16 + lk * 4 + j) * 16 + lr;
                int sw   = (((pair >> 3) & 1) << 3) | (((pair >> 6) & 1) << 4);
                *(unsigned*)&raw16[pair * 40 + (c0 ^ sw)] = pack2f16(acc[0][rh][j], acc[1][rh][j]);
            }
        }
    }

    // W2 fragments (A-operand: row p = c8*16+lr, k-slice c = lk*8) + bias quads
    half8 wfrag[8]; float4 b2q[8];
    #pragma unroll
    for (int c8 = 0; c8 < 8; ++c8) {
        const float* wp = W2 + (size_t)(c8 * 16 + lr) * 32 + lk * 8;
        wfrag[c8] = cvt8(*(const float4*)wp, *(const float4*)(wp + 4));
        b2q[c8]   = *(const float4*)(b2 + c8 * 16 + lk * 4);
    }
    __syncthreads();

    // ---- phase B: wave w handles l-rows r in [8w, 8w+8) ----
    for (int i = 0; i < 8; ++i) {
        const int r  = w * 8 + i;
        const int pr = r * 16 + lr;
        const int swr = (((pr >> 3) & 1) << 3) | (((pr >> 6) & 1) << 4);
        half8 a = *(const half8*)&raw16[pr * 40 + ((lk * 8) ^ swr)];   // B-frag: col=pair(m), k=c

        // compute D[p][m] for 16 m, 128 p; park in per-wave swizzled scratch
        #pragma unroll
        for (int c8 = 0; c8 < 8; ++c8) {
            f32x4 d = { b2q[c8].x, b2q[c8].y, b2q[c8].z, b2q[c8].w };
            d = MFMA_F16(wfrag[c8], a, d);
            // lane (lr,lk) holds p = c8*16+lk*4+j for m = lr
            int chunk = (c8 * 4 + lk) ^ lr;        // 16B-chunk swizzle by m-row
            *(f32x4*)&sc[w][lr * 128 + chunk * 4] = d;
        }
        // read back in store order: 8 x 1KB contiguous (full 8KB region for this l-row)
        float* ob = out + (((size_t)(b * 512 + l0 + r)) * 512 + m0) * 128;
        #pragma unroll
        for (int s = 0; s < 8; ++s) {
            int mm = s * 2 + (lane >> 5);
            int cp = (lane & 31) ^ mm;
            f32x4 v = *(const f32x4*)&sc[w][mm * 128 + cp * 4];
            __builtin_nontemporal_store(v, (f32x4*)(ob + s * 256 + lane * 4));
        }
    }
}

extern "C" void kernel_launch(void* const* d_in, const int* in_sizes, int n_in,
                              void* d_out, int out_size, void* d_ws, size_t ws_size,
                              hipStream_t stream) {
    const float* x    = (const float*)d_in[0];
    const float* ln_w = (const float*)d_in[1];
    const float* ln_b = (const float*)d_in[2];
    const float* W1   = (const float*)d_in[3];
    const float* b1   = (const float*)d_in[4];
    const float* Wa   = (const float*)d_in[5];
    const float* ba   = (const float*)d_in[6];
    const float* W2   = (const float*)d_in[7];
    const float* b2   = (const float*)d_in[8];
    float* out = (float*)d_out;

    _Float16* mo  = (_Float16*)d_ws;                     // [2,32,512,64] f16 = 4 MB
    _Float16* mt  = mo + (size_t)2 * 32 * 512 * 64;      // [2,32,512,64] f16 = 4 MB
    _Float16* W1H = mt + (size_t)2 * 32 * 512 * 64;      // 128 KB packed f16 W1

    k0_pack<<<32, 256, 0, stream>>>(W1, W1H);
    k1_rowstage<<<1024, 256, 0, stream>>>(x, ln_w, ln_b, W1H, b1, Wa, ba, mo, mt);
    k2_mfma<<<1024, 256, 0, stream>>>(mo, mt, W2, b2, out);
}

// Round 12
// 77.257 us; speedup vs baseline: 1.9702x; 1.0125x over previous
//
#include <hip/hip_runtime.h>
#include <math.h>

// B=2, L=512, C=768, C/3=256, pairDim=128
// ws: mo [2,32,512,64] f16 (4 MB) | mt same (4 MB) | W1H f16 frag-packed 128 KB
// k1 batches 4 rows/block (256 blocks): W1H L2 traffic /4, 12/16 MFMA A-rows used.

typedef __attribute__((ext_vector_type(8))) _Float16 half8;
typedef __attribute__((ext_vector_type(4))) _Float16 half4;
typedef __attribute__((ext_vector_type(4))) float f32x4;

#define MFMA_F16(a,b,c) __builtin_amdgcn_mfma_f32_16x16x32_f16((a),(b),(c),0,0,0)

static __device__ inline unsigned pack2f16(float a, float b) {
    _Float16 ha = (_Float16)a, hb = (_Float16)b;
    unsigned short ua = __builtin_bit_cast(unsigned short, ha);
    unsigned short ub = __builtin_bit_cast(unsigned short, hb);
    return (unsigned)ua | ((unsigned)ub << 16);
}

static __device__ inline half8 cvt8(float4 u, float4 v) {
    half8 h;
    h[0] = (_Float16)u.x; h[1] = (_Float16)u.y; h[2] = (_Float16)u.z; h[3] = (_Float16)u.w;
    h[4] = (_Float16)v.x; h[5] = (_Float16)v.y; h[6] = (_Float16)v.z; h[7] = (_Float16)v.w;
    return h;
}

// k0: W1 [256 j][256 i] f32 -> W1H f16 B-frag order [nt][ks][lane][8]
__global__ __launch_bounds__(256) void k0_pack(const float* __restrict__ W1, _Float16* __restrict__ W1H)
{
    int flat8 = blockIdx.x * 256 + threadIdx.x;   // 0..8191 (8-elem chunks)
    int j  = flat8 >> 5, i8 = flat8 & 31;
    int nt = j >> 4, lr = j & 15, ks = i8 >> 2, lk = i8 & 3;
    const float4* src = (const float4*)(W1 + (size_t)j * 256 + (size_t)i8 * 8);
    half8 h = cvt8(src[0], src[1]);
    *(half8*)(W1H + (((size_t)(nt * 8 + ks) * 64) + lk * 16 + lr) * 8) = h;
}

// k1: 256 blocks x 256 threads; block handles rows l0..l0+3 of batch b.
__global__ __launch_bounds__(256) void k1_rowstage4(
    const float* __restrict__ x, const float* __restrict__ ln_w, const float* __restrict__ ln_b,
    const _Float16* __restrict__ W1H, const float* __restrict__ b1,
    const float* __restrict__ Wa, const float* __restrict__ ba,
    _Float16* __restrict__ mo_g, _Float16* __restrict__ mt_g)
{
    const int blk = blockIdx.x;
    const int b   = blk >> 7;
    const int l0  = (blk & 127) << 2;    // 4 rows
    const int tid = threadIdx.x;
    const int w   = tid >> 6;            // wave; LN row = w
    const int lane = tid & 63;
    const int lr  = lane & 15;
    const int lk  = lane >> 4;

    __shared__ _Float16 hs16[16 * 280];  // A rows m=r*3+k (12 used), stride 280 (16B-mult, <=2-way)
    __shared__ float ts4[4][776];        // t per row, pad 8
    __shared__ float mos4[4][2176];      // mean_out per row, stride 68

    // Wa fragments for GEMM2 (A-op: row d=w*16+lr, k-slice e=ks*32+lk*8) — issue early
    half8 waf[2];
    #pragma unroll
    for (int ks = 0; ks < 2; ++ks) {
        const float* wp = Wa + (size_t)(w * 16 + lr) * 64 + ks * 32 + lk * 8;
        waf[ks] = cvt8(*(const float4*)wp, *(const float4*)(wp + 4));
    }
    const float4 baq = *(const float4*)(ba + w * 16 + lk * 4);

    // ---- LN: wave w owns row l0+w; 3 float4/lane; wave-local butterfly reduce ----
    {
        const float4* xrow = (const float4*)(x + ((size_t)(b * 512 + l0 + w)) * 768);
        float4 xv[3];
        float s1 = 0.f, s2 = 0.f;
        #pragma unroll
        for (int e4 = 0; e4 < 3; ++e4) {
            float4 v = xrow[lane + 64 * e4];
            xv[e4] = v;
            s1 += v.x + v.y + v.z + v.w;
            s2 += v.x * v.x + v.y * v.y + v.z * v.z + v.w * v.w;
        }
        #pragma unroll
        for (int off = 32; off > 0; off >>= 1) {
            s1 += __shfl_xor(s1, off);
            s2 += __shfl_xor(s2, off);
        }
        float mu   = s1 * (1.0f / 768.0f);
        float var  = s2 * (1.0f / 768.0f) - mu * mu;
        float rstd = rsqrtf(var + 1e-6f);
        #pragma unroll
        for (int e4 = 0; e4 < 3; ++e4) {
            float4 lw = ((const float4*)ln_w)[lane + 64 * e4];
            float4 lb = ((const float4*)ln_b)[lane + 64 * e4];
            half4 h4;
            h4[0] = (_Float16)((xv[e4].x - mu) * rstd * lw.x + lb.x);
            h4[1] = (_Float16)((xv[e4].y - mu) * rstd * lw.y + lb.y);
            h4[2] = (_Float16)((xv[e4].z - mu) * rstd * lw.z + lb.z);
            h4[3] = (_Float16)((xv[e4].w - mu) * rstd * lw.w + lb.w);
            // chunk k = e4, elem i = 4*lane; A row m = w*3 + e4
            *(half4*)&hs16[(w * 3 + e4) * 280 + 4 * lane] = h4;
        }
    }
    __syncthreads();

    // ---- GEMM1 (MFMA): t[r][k][j] = h[r][k] . W1[j,:] + b1[j]; A rows m=r*3+k ----
    {
        f32x4 acc[4] = {};
        #pragma unroll
        for (int ks = 0; ks < 8; ++ks) {
            half8 af = *(const half8*)&hs16[lr * 280 + ks * 32 + lk * 8];
            #pragma unroll
            for (int n = 0; n < 4; ++n) {
                half8 bf = *(const half8*)(W1H + (((size_t)((w * 4 + n) * 8 + ks) * 64) + lane) * 8);
                acc[n] = MFMA_F16(af, bf, acc[n]);
            }
        }
        #pragma unroll
        for (int n = 0; n < 4; ++n) {
            int j = (w * 4 + n) * 16 + lr;
            float bb = b1[j];
            #pragma unroll
            for (int jj = 0; jj < 4; ++jj) {
                int m = lk * 4 + jj;          // compile-time per (lk? no: lk runtime) — m<12 guard
                if (m < 12) {
                    int r = m / 3, k = m - r * 3;
                    ts4[r][k * 256 + j] = acc[n][jj] + bb;
                }
            }
        }
    }
    __syncthreads();

    // ---- outer product -> mos4 + mo_g (f16), per row ----
    {
        const int c = tid >> 3, i = tid & 7;
        #pragma unroll
        for (int r = 0; r < 4; ++r) {
            float ti0 = ts4[r][c * 8 + i], ti1 = ts4[r][256 + c * 8 + i], ti2 = ts4[r][512 + c * 8 + i];
            half8 h8;
            #pragma unroll
            for (int j = 0; j < 8; j++) {
                float m = (ti0 * ts4[r][c * 8 + j] + ti1 * ts4[r][256 + c * 8 + j]
                         + ti2 * ts4[r][512 + c * 8 + j]) * (1.0f / 3.0f);
                mos4[r][c * 68 + i * 8 + j] = m;
                h8[j] = (_Float16)m;
            }
            size_t mobase = ((size_t)(b * 32 + c) * 512 + (l0 + r)) * 64 + i * 8;
            *(half8*)(mo_g + mobase) = h8;
        }
    }
    __syncthreads();

    // ---- GEMM2 (MFMA): mt[d][c] = gelu(Wa . mo_r + ba), 8 n-tiles = 4 rows x 2 c-halves ----
    #pragma unroll
    for (int nt2 = 0; nt2 < 8; ++nt2) {
        const int r = nt2 >> 1, ch = nt2 & 1;
        f32x4 acc = { baq.x, baq.y, baq.z, baq.w };
        #pragma unroll
        for (int ks = 0; ks < 2; ++ks) {
            const float* mp = &mos4[r][(ch * 16 + lr) * 68 + ks * 32 + lk * 8];
            half8 mof = cvt8(*(const float4*)mp, *(const float4*)(mp + 4));
            acc = MFMA_F16(waf[ks], mof, acc);
        }
        half4 o;
        #pragma unroll
        for (int j = 0; j < 4; ++j) {
            float g = 0.5f * acc[j] * (1.0f + erff(acc[j] * 0.70710678118654752f));
            o[j] = (_Float16)g;
        }
        *(half4*)(mt_g + ((size_t)(b * 32 + ch * 16 + lr) * 512 + (l0 + r)) * 64 + w * 16 + lk * 4) = o;
    }
}

// k2 (R4 verbatim): per (32 l x 16 m) tile:
//   phase A (MFMA): raw[pair][c] = MO[c,l,:].MT[c,m,:] -> f16 in LDS (pad 40, XOR-swizzled)
//   phase B (MFMA): D[p][pair] = W2 . raw; per-wave LDS transpose ->
//                   8 x 1KB-contiguous nontemporal f32x4 stores per l-row
__global__ __launch_bounds__(256, 2) void k2_mfma(
    const _Float16* __restrict__ mo, const _Float16* __restrict__ mt,
    const float* __restrict__ W2, const float* __restrict__ b2,
    float* __restrict__ out)
{
    __shared__ _Float16 raw16[512 * 40];   // [pair][c], 80B rows, 40 KB
    __shared__ float sc[4][2048];          // per-wave 8KB transpose scratch, 32 KB

    const int tid  = threadIdx.x;
    const int w    = tid >> 6;
    const int lane = tid & 63;
    const int lr   = lane & 15;
    const int lk   = lane >> 4;

    // bijective XCD swizzle (nwg=1024, 1024%8==0)
    const int flat = blockIdx.x;
    const int nf   = (flat & 7) * 128 + (flat >> 3);
    const int m0   = (nf & 31) << 4;        // 32 m-tiles of 16
    const int l0   = ((nf >> 5) & 15) << 5; // 16 l-tiles of 32
    const int b    = nf >> 9;

    // ---- phase A: wave w computes c in [8w, 8w+8), all 512 pairs ----
    #pragma unroll
    for (int cp = 0; cp < 4; ++cp) {
        const int c0 = w * 8 + cp * 2;
        f32x4 acc[2][2] = {};   // [ci][rh]
        #pragma unroll
        for (int ci = 0; ci < 2; ++ci) {
            const int c = c0 + ci;
            const _Float16* mo_c = mo + (((size_t)(b * 32 + c) * 512) + l0) * 64;
            const _Float16* mt_c = mt + (((size_t)(b * 32 + c) * 512) + m0) * 64;
            #pragma unroll
            for (int ks = 0; ks < 2; ++ks) {
                half8 bfrag = *(const half8*)(mt_c + (size_t)lr * 64 + ks * 32 + lk * 8);
                #pragma unroll
                for (int rh = 0; rh < 2; ++rh) {
                    half8 afrag = *(const half8*)(mo_c + (size_t)(rh * 16 + lr) * 64 + ks * 32 + lk * 8);
                    acc[ci][rh] = MFMA_F16(afrag, bfrag, acc[ci][rh]);
                }
            }
        }
        // park raw tile: pair = l_local*16 + m_local; D: row(l)=lk*4+j, col(m)=lr
        #pragma unroll
        for (int rh = 0; rh < 2; ++rh) {
            #pragma unroll
            for (int j = 0; j < 4; ++j) {
                int pair = (rh * 16 + lk * 4 + j) * 16 + lr;
                int sw   = (((pair >> 3) & 1) << 3) | (((pair >> 6) & 1) << 4);
                *(unsigned*)&raw16[pair * 40 + (c0 ^ sw)] = pack2f16(acc[0][rh][j], acc[1][rh][j]);
            }
        }
    }

    // W2 fragments (A-operand: row p = c8*16+lr, k-slice c = lk*8) + bias quads
    half8 wfrag[8]; float4 b2q[8];
    #pragma unroll
    for (int c8 = 0; c8 < 8; ++c8) {
        const float* wp = W2 + (size_t)(c8 * 16 + lr) * 32 + lk * 8;
        wfrag[c8] = cvt8(*(const float4*)wp, *(const float4*)(wp + 4));
        b2q[c8]   = *(const float4*)(b2 + c8 * 16 + lk * 4);
    }
    __syncthreads();

    // ---- phase B: wave w handles l-rows r in [8w, 8w+8) ----
    for (int i = 0; i < 8; ++i) {
        const int r  = w * 8 + i;
        const int pr = r * 16 + lr;
        const int swr = (((pr >> 3) & 1) << 3) | (((pr >> 6) & 1) << 4);
        half8 a = *(const half8*)&raw16[pr * 40 + ((lk * 8) ^ swr)];   // B-frag: col=pair(m), k=c

        // compute D[p][m] for 16 m, 128 p; park in per-wave swizzled scratch
        #pragma unroll
        for (int c8 = 0; c8 < 8; ++c8) {
            f32x4 d = { b2q[c8].x, b2q[c8].y, b2q[c8].z, b2q[c8].w };
            d = MFMA_F16(wfrag[c8], a, d);
            // lane (lr,lk) holds p = c8*16+lk*4+j for m = lr
            int chunk = (c8 * 4 + lk) ^ lr;        // 16B-chunk swizzle by m-row
            *(f32x4*)&sc[w][lr * 128 + chunk * 4] = d;
        }
        // read back in store order: 8 x 1KB contiguous (full 8KB region for this l-row)
        float* ob = out + (((size_t)(b * 512 + l0 + r)) * 512 + m0) * 128;
        #pragma unroll
        for (int s = 0; s < 8; ++s) {
            int mm = s * 2 + (lane >> 5);
            int cp = (lane & 31) ^ mm;
            f32x4 v = *(const f32x4*)&sc[w][mm * 128 + cp * 4];
            __builtin_nontemporal_store(v, (f32x4*)(ob + s * 256 + lane * 4));
        }
    }
}

extern "C" void kernel_launch(void* const* d_in, const int* in_sizes, int n_in,
                              void* d_out, int out_size, void* d_ws, size_t ws_size,
                              hipStream_t stream) {
    const float* x    = (const float*)d_in[0];
    const float* ln_w = (const float*)d_in[1];
    const float* ln_b = (const float*)d_in[2];
    const float* W1   = (const float*)d_in[3];
    const float* b1   = (const float*)d_in[4];
    const float* Wa   = (const float*)d_in[5];
    const float* ba   = (const float*)d_in[6];
    const float* W2   = (const float*)d_in[7];
    const float* b2   = (const float*)d_in[8];
    float* out = (float*)d_out;

    _Float16* mo  = (_Float16*)d_ws;                     // [2,32,512,64] f16 = 4 MB
    _Float16* mt  = mo + (size_t)2 * 32 * 512 * 64;      // [2,32,512,64] f16 = 4 MB
    _Float16* W1H = mt + (size_t)2 * 32 * 512 * 64;      // 128 KB packed f16 W1

    k0_pack<<<32, 256, 0, stream>>>(W1, W1H);
    k1_rowstage4<<<256, 256, 0, stream>>>(x, ln_w, ln_b, W1H, b1, Wa, ba, mo, mt);
    k2_mfma<<<1024, 256, 0, stream>>>(mo, mt, W2, b2, out);
}

// Round 13
// 76.290 us; speedup vs baseline: 1.9952x; 1.0127x over previous
//
#include <hip/hip_runtime.h>
#include <math.h>

// B=2, L=512, C=768, C/3=256, pairDim=128
// ws: mo [2,32,512,64] f16 (4 MB) | mt same (4 MB) | W1H f16 frag-packed 128 KB
// k1: 512 blocks x 2 rows (midpoint of R11/R12): 8 waves/CU + 2x-reduced W1H traffic.

typedef __attribute__((ext_vector_type(8))) _Float16 half8;
typedef __attribute__((ext_vector_type(4))) _Float16 half4;
typedef __attribute__((ext_vector_type(4))) float f32x4;

#define MFMA_F16(a,b,c) __builtin_amdgcn_mfma_f32_16x16x32_f16((a),(b),(c),0,0,0)

static __device__ inline unsigned pack2f16(float a, float b) {
    _Float16 ha = (_Float16)a, hb = (_Float16)b;
    unsigned short ua = __builtin_bit_cast(unsigned short, ha);
    unsigned short ub = __builtin_bit_cast(unsigned short, hb);
    return (unsigned)ua | ((unsigned)ub << 16);
}

static __device__ inline half8 cvt8(float4 u, float4 v) {
    half8 h;
    h[0] = (_Float16)u.x; h[1] = (_Float16)u.y; h[2] = (_Float16)u.z; h[3] = (_Float16)u.w;
    h[4] = (_Float16)v.x; h[5] = (_Float16)v.y; h[6] = (_Float16)v.z; h[7] = (_Float16)v.w;
    return h;
}

// k0: W1 [256 j][256 i] f32 -> W1H f16 B-frag order [nt][ks][lane][8]
__global__ __launch_bounds__(256) void k0_pack(const float* __restrict__ W1, _Float16* __restrict__ W1H)
{
    int flat8 = blockIdx.x * 256 + threadIdx.x;   // 0..8191 (8-elem chunks)
    int j  = flat8 >> 5, i8 = flat8 & 31;
    int nt = j >> 4, lr = j & 15, ks = i8 >> 2, lk = i8 & 3;
    const float4* src = (const float4*)(W1 + (size_t)j * 256 + (size_t)i8 * 8);
    half8 h = cvt8(src[0], src[1]);
    *(half8*)(W1H + (((size_t)(nt * 8 + ks) * 64) + lk * 16 + lr) * 8) = h;
}

// k1: 512 blocks x 256 threads; block handles rows l0, l0+1 of batch b.
__global__ __launch_bounds__(256) void k1_rowstage2(
    const float* __restrict__ x, const float* __restrict__ ln_w, const float* __restrict__ ln_b,
    const _Float16* __restrict__ W1H, const float* __restrict__ b1,
    const float* __restrict__ Wa, const float* __restrict__ ba,
    _Float16* __restrict__ mo_g, _Float16* __restrict__ mt_g)
{
    const int blk = blockIdx.x;
    const int b   = blk >> 8;
    const int l0  = (blk & 255) << 1;    // 2 rows
    const int tid = threadIdx.x;
    const int w   = tid >> 6;
    const int lane = tid & 63;
    const int lr  = lane & 15;
    const int lk  = lane >> 4;

    __shared__ _Float16 hs16[16 * 280];  // A rows m=r*3+k (6 used; 6-15 garbage, D-rows unread)
    __shared__ float ts2[2][776];        // t per row, pad 8
    __shared__ float mos2[2][2176];      // mean_out per row, stride 68

    // Wa fragments for GEMM2 (A-op: row d=w*16+lr, k-slice e=ks*32+lk*8)
    half8 waf[2];
    #pragma unroll
    for (int ks = 0; ks < 2; ++ks) {
        const float* wp = Wa + (size_t)(w * 16 + lr) * 64 + ks * 32 + lk * 8;
        waf[ks] = cvt8(*(const float4*)wp, *(const float4*)(wp + 4));
    }
    const float4 baq = *(const float4*)(ba + w * 16 + lk * 4);

    // ---- LN: waves 0,1 own rows l0+w; 3 float4/lane; wave-local butterfly reduce ----
    if (w < 2) {
        const float4* xrow = (const float4*)(x + ((size_t)(b * 512 + l0 + w)) * 768);
        float4 xv[3];
        float s1 = 0.f, s2 = 0.f;
        #pragma unroll
        for (int e4 = 0; e4 < 3; ++e4) {
            float4 v = xrow[lane + 64 * e4];
            xv[e4] = v;
            s1 += v.x + v.y + v.z + v.w;
            s2 += v.x * v.x + v.y * v.y + v.z * v.z + v.w * v.w;
        }
        #pragma unroll
        for (int off = 32; off > 0; off >>= 1) {
            s1 += __shfl_xor(s1, off);
            s2 += __shfl_xor(s2, off);
        }
        float mu   = s1 * (1.0f / 768.0f);
        float var  = s2 * (1.0f / 768.0f) - mu * mu;
        float rstd = rsqrtf(var + 1e-6f);
        #pragma unroll
        for (int e4 = 0; e4 < 3; ++e4) {
            float4 lw = ((const float4*)ln_w)[lane + 64 * e4];
            float4 lb = ((const float4*)ln_b)[lane + 64 * e4];
            half4 h4;
            h4[0] = (_Float16)((xv[e4].x - mu) * rstd * lw.x + lb.x);
            h4[1] = (_Float16)((xv[e4].y - mu) * rstd * lw.y + lb.y);
            h4[2] = (_Float16)((xv[e4].z - mu) * rstd * lw.z + lb.z);
            h4[3] = (_Float16)((xv[e4].w - mu) * rstd * lw.w + lb.w);
            // chunk k = e4, elem i = 4*lane; A row m = w*3 + e4
            *(half4*)&hs16[(w * 3 + e4) * 280 + 4 * lane] = h4;
        }
    }
    __syncthreads();

    // ---- GEMM1 (MFMA): t[r][k][j] = h[r][k] . W1[j,:] + b1[j]; A rows m=r*3+k < 6 ----
    {
        f32x4 acc[4] = {};
        #pragma unroll
        for (int ks = 0; ks < 8; ++ks) {
            half8 af = *(const half8*)&hs16[lr * 280 + ks * 32 + lk * 8];
            #pragma unroll
            for (int n = 0; n < 4; ++n) {
                half8 bf = *(const half8*)(W1H + (((size_t)((w * 4 + n) * 8 + ks) * 64) + lane) * 8);
                acc[n] = MFMA_F16(af, bf, acc[n]);
            }
        }
        #pragma unroll
        for (int n = 0; n < 4; ++n) {
            int j = (w * 4 + n) * 16 + lr;
            float bb = b1[j];
            #pragma unroll
            for (int jj = 0; jj < 4; ++jj) {
                int m = lk * 4 + jj;
                if (m < 6) {
                    int r = (m >= 3) ? 1 : 0, k = m - r * 3;
                    ts2[r][k * 256 + j] = acc[n][jj] + bb;
                }
            }
        }
    }
    __syncthreads();

    // ---- outer product -> mos2 + mo_g (f16), per row ----
    {
        const int c = tid >> 3, i = tid & 7;
        #pragma unroll
        for (int r = 0; r < 2; ++r) {
            float ti0 = ts2[r][c * 8 + i], ti1 = ts2[r][256 + c * 8 + i], ti2 = ts2[r][512 + c * 8 + i];
            half8 h8;
            #pragma unroll
            for (int j = 0; j < 8; j++) {
                float m = (ti0 * ts2[r][c * 8 + j] + ti1 * ts2[r][256 + c * 8 + j]
                         + ti2 * ts2[r][512 + c * 8 + j]) * (1.0f / 3.0f);
                mos2[r][c * 68 + i * 8 + j] = m;
                h8[j] = (_Float16)m;
            }
            size_t mobase = ((size_t)(b * 32 + c) * 512 + (l0 + r)) * 64 + i * 8;
            *(half8*)(mo_g + mobase) = h8;
        }
    }
    __syncthreads();

    // ---- GEMM2 (MFMA): mt[d][c] = gelu(Wa . mo_r + ba); 4 n-tiles = 2 rows x 2 c-halves ----
    #pragma unroll
    for (int nt2 = 0; nt2 < 4; ++nt2) {
        const int r = nt2 >> 1, ch = nt2 & 1;
        f32x4 acc = { baq.x, baq.y, baq.z, baq.w };
        #pragma unroll
        for (int ks = 0; ks < 2; ++ks) {
            const float* mp = &mos2[r][(ch * 16 + lr) * 68 + ks * 32 + lk * 8];
            half8 mof = cvt8(*(const float4*)mp, *(const float4*)(mp + 4));
            acc = MFMA_F16(waf[ks], mof, acc);
        }
        half4 o;
        #pragma unroll
        for (int j = 0; j < 4; ++j) {
            float g = 0.5f * acc[j] * (1.0f + erff(acc[j] * 0.70710678118654752f));
            o[j] = (_Float16)g;
        }
        *(half4*)(mt_g + ((size_t)(b * 32 + ch * 16 + lr) * 512 + (l0 + r)) * 64 + w * 16 + lk * 4) = o;
    }
}

// k2 (R4 verbatim): per (32 l x 16 m) tile:
//   phase A (MFMA): raw[pair][c] = MO[c,l,:].MT[c,m,:] -> f16 in LDS (pad 40, XOR-swizzled)
//   phase B (MFMA): D[p][pair] = W2 . raw; per-wave LDS transpose ->
//                   8 x 1KB-contiguous nontemporal f32x4 stores per l-row
__global__ __launch_bounds__(256, 2) void k2_mfma(
    const _Float16* __restrict__ mo, const _Float16* __restrict__ mt,
    const float* __restrict__ W2, const float* __restrict__ b2,
    float* __restrict__ out)
{
    __shared__ _Float16 raw16[512 * 40];   // [pair][c], 80B rows, 40 KB
    __shared__ float sc[4][2048];          // per-wave 8KB transpose scratch, 32 KB

    const int tid  = threadIdx.x;
    const int w    = tid >> 6;
    const int lane = tid & 63;
    const int lr   = lane & 15;
    const int lk   = lane >> 4;

    // bijective XCD swizzle (nwg=1024, 1024%8==0)
    const int flat = blockIdx.x;
    const int nf   = (flat & 7) * 128 + (flat >> 3);
    const int m0   = (nf & 31) << 4;        // 32 m-tiles of 16
    const int l0   = ((nf >> 5) & 15) << 5; // 16 l-tiles of 32
    const int b    = nf >> 9;

    // ---- phase A: wave w computes c in [8w, 8w+8), all 512 pairs ----
    #pragma unroll
    for (int cp = 0; cp < 4; ++cp) {
        const int c0 = w * 8 + cp * 2;
        f32x4 acc[2][2] = {};   // [ci][rh]
        #pragma unroll
        for (int ci = 0; ci < 2; ++ci) {
            const int c = c0 + ci;
            const _Float16* mo_c = mo + (((size_t)(b * 32 + c) * 512) + l0) * 64;
            const _Float16* mt_c = mt + (((size_t)(b * 32 + c) * 512) + m0) * 64;
            #pragma unroll
            for (int ks = 0; ks < 2; ++ks) {
                half8 bfrag = *(const half8*)(mt_c + (size_t)lr * 64 + ks * 32 + lk * 8);
                #pragma unroll
                for (int rh = 0; rh < 2; ++rh) {
                    half8 afrag = *(const half8*)(mo_c + (size_t)(rh * 16 + lr) * 64 + ks * 32 + lk * 8);
                    acc[ci][rh] = MFMA_F16(afrag, bfrag, acc[ci][rh]);
                }
            }
        }
        // park raw tile: pair = l_local*16 + m_local; D: row(l)=lk*4+j, col(m)=lr
        #pragma unroll
        for (int rh = 0; rh < 2; ++rh) {
            #pragma unroll
            for (int j = 0; j < 4; ++j) {
                int pair = (rh * 16 + lk * 4 + j) * 16 + lr;
                int sw   = (((pair >> 3) & 1) << 3) | (((pair >> 6) & 1) << 4);
                *(unsigned*)&raw16[pair * 40 + (c0 ^ sw)] = pack2f16(acc[0][rh][j], acc[1][rh][j]);
            }
        }
    }

    // W2 fragments (A-operand: row p = c8*16+lr, k-slice c = lk*8) + bias quads
    half8 wfrag[8]; float4 b2q[8];
    #pragma unroll
    for (int c8 = 0; c8 < 8; ++c8) {
        const float* wp = W2 + (size_t)(c8 * 16 + lr) * 32 + lk * 8;
        wfrag[c8] = cvt8(*(const float4*)wp, *(const float4*)(wp + 4));
        b2q[c8]   = *(const float4*)(b2 + c8 * 16 + lk * 4);
    }
    __syncthreads();

    // ---- phase B: wave w handles l-rows r in [8w, 8w+8) ----
    for (int i = 0; i < 8; ++i) {
        const int r  = w * 8 + i;
        const int pr = r * 16 + lr;
        const int swr = (((pr >> 3) & 1) << 3) | (((pr >> 6) & 1) << 4);
        half8 a = *(const half8*)&raw16[pr * 40 + ((lk * 8) ^ swr)];   // B-frag: col=pair(m), k=c

        // compute D[p][m] for 16 m, 128 p; park in per-wave swizzled scratch
        #pragma unroll
        for (int c8 = 0; c8 < 8; ++c8) {
            f32x4 d = { b2q[c8].x, b2q[c8].y, b2q[c8].z, b2q[c8].w };
            d = MFMA_F16(wfrag[c8], a, d);
            // lane (lr,lk) holds p = c8*16+lk*4+j for m = lr
            int chunk = (c8 * 4 + lk) ^ lr;        // 16B-chunk swizzle by m-row
            *(f32x4*)&sc[w][lr * 128 + chunk * 4] = d;
        }
        // read back in store order: 8 x 1KB contiguous (full 8KB region for this l-row)
        float* ob = out + (((size_t)(b * 512 + l0 + r)) * 512 + m0) * 128;
        #pragma unroll
        for (int s = 0; s < 8; ++s) {
            int mm = s * 2 + (lane >> 5);
            int cp = (lane & 31) ^ mm;
            f32x4 v = *(const f32x4*)&sc[w][mm * 128 + cp * 4];
            __builtin_nontemporal_store(v, (f32x4*)(ob + s * 256 + lane * 4));
        }
    }
}

extern "C" void kernel_launch(void* const* d_in, const int* in_sizes, int n_in,
                              void* d_out, int out_size, void* d_ws, size_t ws_size,
                              hipStream_t stream) {
    const float* x    = (const float*)d_in[0];
    const float* ln_w = (const float*)d_in[1];
    const float* ln_b = (const float*)d_in[2];
    const float* W1   = (const float*)d_in[3];
    const float* b1   = (const float*)d_in[4];
    const float* Wa   = (const float*)d_in[5];
    const float* ba   = (const float*)d_in[6];
    const float* W2   = (const float*)d_in[7];
    const float* b2   = (const float*)d_in[8];
    float* out = (float*)d_out;

    _Float16* mo  = (_Float16*)d_ws;                     // [2,32,512,64] f16 = 4 MB
    _Float16* mt  = mo + (size_t)2 * 32 * 512 * 64;      // [2,32,512,64] f16 = 4 MB
    _Float16* W1H = mt + (size_t)2 * 32 * 512 * 64;      // 128 KB packed f16 W1

    k0_pack<<<32, 256, 0, stream>>>(W1, W1H);
    k1_rowstage2<<<512, 256, 0, stream>>>(x, ln_w, ln_b, W1H, b1, Wa, ba, mo, mt);
    k2_mfma<<<1024, 256, 0, stream>>>(mo, mt, W2, b2, out);
}